// Round 10
// baseline (395.680 us; speedup 1.0000x reference)
//
#include <hip/hip_runtime.h>
#include <hip/hip_bf16.h>

typedef unsigned short u16;
typedef unsigned int   uint;
typedef __attribute__((ext_vector_type(8))) short bf16x8;
typedef __attribute__((ext_vector_type(4))) float f32x4;

constexpr int NELEM = 100;
constexpr int EMBED = 256;
constexpr int HID   = 512;
constexpr int KX    = 306;     // EMBED + 50
constexpr int G     = 50;
constexpr int M     = 64;      // edges per block
constexpr int THREADS = 512;   // 8 waves

// frag-ready weight buffers in d_ws (bf16):
//  Wb : [32 nt][10 ks][64 lane][8]   (k==306 row carries b_in; >306 zero)
//  Gb : [32 nt][ 2 ks][64 lane][8]   (g>=50 zero)
//  Ob : [16 slice][64 lane][8]       permuted W_out for in-register out-proj
//  Eb : emb_table converted to bf16 (if ws fits)
constexpr int WB_ELEMS = 32 * 10 * 64 * 8;
constexpr int GB_ELEMS = 32 * 2 * 64 * 8;
constexpr int OB_ELEMS = 16 * 64 * 8;
constexpr int WEIGHT_ELEMS = WB_ELEMS + GB_ELEMS + OB_ELEMS;   // 204800

__device__ __forceinline__ u16 f2bf(float x) {
    uint u = __float_as_uint(x);
    u = (u + 0x7fffu + ((u >> 16) & 1u)) >> 16;
    return (u16)u;
}
__device__ __forceinline__ uint pk2(float a, float b) {
    __hip_bfloat162 h = __float22bfloat162_rn(make_float2(a, b));
    return *reinterpret_cast<uint*>(&h);
}
__device__ __forceinline__ float silu(float p) {
    return p * __builtin_amdgcn_rcpf(1.f + __expf(-p));
}
__device__ __forceinline__ f32x4 mfma16(bf16x8 a, bf16x8 b, f32x4 c) {
    return __builtin_amdgcn_mfma_f32_16x16x32_bf16(a, b, c, 0, 0, 0);
}
__device__ __forceinline__ void load_lds16(const u16* g, u16* l) {
    __builtin_amdgcn_global_load_lds(
        (const __attribute__((address_space(1))) uint*)g,
        (__attribute__((address_space(3))) uint*)l, 16, 0, 0);
}

// ---- prep: weights -> frag layouts, plus emb_table f32->bf16 (fused) -------
__global__ void prep_all_kernel(const float* __restrict__ W_in,   // [512][306]
                                const float* __restrict__ gate_W, // [512][50]
                                const float* __restrict__ W_out,  // [8][512]
                                const float* __restrict__ b_in,   // [512]
                                const float* __restrict__ table,  // emb f32
                                u16* __restrict__ Wb,
                                u16* __restrict__ Gb,
                                u16* __restrict__ Ob,
                                uint* __restrict__ Eb4,           // bf16 table
                                int nconv, int do_conv) {
    int idx = blockIdx.x * 256 + threadIdx.x;
    if (idx < WB_ELEMS) {
        int j = idx & 7, lane = (idx >> 3) & 63, kn = idx >> 9;
        int ks = kn % 10, nt = kn / 10;
        int h = nt * 16 + (lane & 15);
        int k = ks * 32 + (lane >> 4) * 8 + j;
        float v = (k < KX) ? W_in[h * KX + k] : ((k == KX) ? b_in[h] : 0.f);
        Wb[idx] = f2bf(v);
    } else if (idx < WB_ELEMS + GB_ELEMS) {
        int i2 = idx - WB_ELEMS;
        int j = i2 & 7, lane = (i2 >> 3) & 63, kn = i2 >> 9;
        int ks = kn & 1, nt = kn >> 1;
        int h = nt * 16 + (lane & 15);
        int g = ks * 32 + (lane >> 4) * 8 + j;
        Gb[i2] = f2bf((g < G) ? gate_W[h * G + g] : 0.f);
    } else if (idx < WEIGHT_ELEMS) {
        int i2 = idx - WB_ELEMS - GB_ELEMS;
        int j = i2 & 7, lane = (i2 >> 3) & 63, s = i2 >> 9;
        int m = lane & 15, q = lane >> 4;
        int hid = s * 32 + (j >> 2) * 16 + q * 4 + (j & 3);
        Ob[i2] = f2bf((m < 8) ? W_out[m * HID + hid] : 0.f);
    } else if (do_conv) {
        int i = idx - WEIGHT_ELEMS;          // one thread = 8 floats -> uint4
        if (i < nconv) {
            const float4* s4 = (const float4*)(table + i * 8);
            float4 v0 = s4[0], v1 = s4[1];
            uint4 w;
            w.x = pk2(v0.x, v0.y); w.y = pk2(v0.z, v0.w);
            w.z = pk2(v1.x, v1.y); w.w = pk2(v1.z, v1.w);
            ((uint4*)Eb4)[i] = w;
        }
    }
}

// ---- fused main kernel (r7 structure + depth-3 weight prefetch) ------------
// Math/accumulation order identical to r7 (merged gate at ks 8..9, f32 gate).
// The 10-ks loop is fully unrolled with a 3-deep rotating register prefetch of
// the wb0/wb1 weight stream so L2 latency hides under MFMA.
template <bool BF16_TABLE>
__global__ __launch_bounds__(THREADS, 4)
void pair_embed_kernel(const int* __restrict__ anum,
                       const int* __restrict__ edge_index,
                       const int* __restrict__ edge_to_src,
                       const float* __restrict__ dist,
                       const float* __restrict__ emb_table,
                       const u16* __restrict__ Eb,
                       const float* __restrict__ b_out,
                       const u16* __restrict__ Wb,
                       const u16* __restrict__ Gb,
                       const u16* __restrict__ Ob,
                       float* __restrict__ out,
                       int E) {
    // afrag [10 ks][4 mt][64 lane][8] = 40 KB; red (32 KB) unions into it.
    __shared__ __align__(16) u16 smem[10 * 4 * 64 * 8];
    __shared__ int   rowbase[M];
    __shared__ float dste[M];
    u16*   afrag = smem;
    float* redf  = (float*)smem;     // [8 wave][4 mt][64 lane][4]

    const int t  = threadIdx.x;
    const int e0 = blockIdx.x * M;
    const int wave = t >> 6, lane = t & 63;
    const int col = lane & 15, quad = lane >> 4;

    if (t < M) {
        int eg = e0 + t;
        int pair = 0; float d = 0.f;
        if (eg < E) {
            int src = edge_to_src[eg];
            pair = anum[edge_index[src]] + NELEM * anum[edge_index[E + src]];
            d = dist[eg];
        }
        rowbase[t] = pair * EMBED;
        dste[t]    = d;
    }
    __syncthreads();

    // ---- stage A-tile -----------------------------------------------------
    {
        if (BF16_TABLE) {
            #pragma unroll
            for (int mt = 0; mt < 4; ++mt) {
                int rb = rowbase[mt * 16 + col];
                const u16* g = Eb + rb + wave * 32 + quad * 8;
                load_lds16(g, &afrag[((wave * 4 + mt) * 64 + lane) * 8]);
            }
        } else {
            #pragma unroll 1
            for (int mt = 0; mt < 4; ++mt) {
                int rb = rowbase[mt * 16 + col];
                const float4* src = (const float4*)(emb_table + rb + wave * 32 + quad * 8);
                float4 v0 = src[0], v1 = src[1];
                uint4 w;
                w.x = pk2(v0.x, v0.y); w.y = pk2(v0.z, v0.w);
                w.z = pk2(v1.x, v1.y); w.w = pk2(v1.z, v1.w);
                *(uint4*)&afrag[((wave * 4 + mt) * 64 + lane) * 8] = w;
            }
        }
        // rbf + bias chunk: one per wave: ks = 8+(wave&1), mt = wave>>1
        {
            const float sp    = 12.0f / 49.0f;
            const float coeff = -0.5f / (sp * sp);
            int ksr = 8 + (wave & 1), mtr = wave >> 1;
            float d  = dste[mtr * 16 + col];
            int   k0 = ksr * 32 + quad * 8;
            float f[8];
            #pragma unroll
            for (int j = 0; j < 8; ++j) {
                int k = k0 + j;
                int g = k - EMBED;
                float dd = d - sp * (float)g;
                f[j] = (g < G) ? __expf(coeff * dd * dd) : ((k == KX) ? 1.f : 0.f);
            }
            uint4 w;
            w.x = pk2(f[0], f[1]); w.y = pk2(f[2], f[3]);
            w.z = pk2(f[4], f[5]); w.w = pk2(f[6], f[7]);
            *(uint4*)&afrag[((ksr * 4 + mtr) * 64 + lane) * 8] = w;
        }
    }
    __syncthreads();

    const f32x4 z4 = {0.f, 0.f, 0.f, 0.f};
    f32x4 oacc[4] = {z4, z4, z4, z4};        // out-proj partials, D[head][edge]

    #pragma unroll
    for (int nh = 0; nh < 2; ++nh) {
        f32x4 acc[2][4], gacc[2][4];
        #pragma unroll
        for (int ntl = 0; ntl < 2; ++ntl)
            #pragma unroll
            for (int mt = 0; mt < 4; ++mt) { acc[ntl][mt] = z4; gacc[ntl][mt] = z4; }

        const u16* wb0 = &Wb[(((wave * 4 + nh * 2 + 0) * 10) * 64 + lane) * 8];
        const u16* wb1 = &Wb[(((wave * 4 + nh * 2 + 1) * 10) * 64 + lane) * 8];
        const u16* gb  = &Gb[((wave * 4 + nh * 2) * 2 * 64 + lane) * 8];

        // preload gate + out-proj frags (used late; issue loads now)
        bf16x8 g00 = *(const bf16x8*)&gb[0];
        bf16x8 g01 = *(const bf16x8*)&gb[512];
        bf16x8 g10 = *(const bf16x8*)&gb[1024];
        bf16x8 g11 = *(const bf16x8*)&gb[1536];
        bf16x8 obf = *(const bf16x8*)&Ob[(((wave << 1) | nh) * 64 + lane) * 8];

        // depth-3 rotating prefetch of the weight stream
        bf16x8 w0p[3], w1p[3];
        #pragma unroll
        for (int i = 0; i < 3; ++i) {
            w0p[i] = *(const bf16x8*)&wb0[i * 512];
            w1p[i] = *(const bf16x8*)&wb1[i * 512];
        }

        #pragma unroll
        for (int ks = 0; ks < 10; ++ks) {
            bf16x8 a[4];
            #pragma unroll
            for (int mt = 0; mt < 4; ++mt)
                a[mt] = *(const bf16x8*)&afrag[((ks * 4 + mt) * 64 + lane) * 8];
            bf16x8 w0 = w0p[ks % 3];
            bf16x8 w1 = w1p[ks % 3];
            if (ks < 7) {                       // refill the slot just consumed
                w0p[ks % 3] = *(const bf16x8*)&wb0[(ks + 3) * 512];
                w1p[ks % 3] = *(const bf16x8*)&wb1[(ks + 3) * 512];
            }
            #pragma unroll
            for (int mt = 0; mt < 4; ++mt)
                acc[0][mt] = mfma16(w0, a[mt], acc[0][mt]);
            #pragma unroll
            for (int mt = 0; mt < 4; ++mt)
                acc[1][mt] = mfma16(w1, a[mt], acc[1][mt]);
            if (ks >= 8) {                      // gate shares the A-fragments
                bf16x8 gA = (ks == 8) ? g00 : g01;
                bf16x8 gB = (ks == 8) ? g10 : g11;
                #pragma unroll
                for (int mt = 0; mt < 4; ++mt)
                    gacc[0][mt] = mfma16(gA, a[mt], gacc[0][mt]);
                #pragma unroll
                for (int mt = 0; mt < 4; ++mt)
                    gacc[1][mt] = mfma16(gB, a[mt], gacc[1][mt]);
            }
        }

        // ---- silu * gate (f32) -> h-frag (B-operand) -> out-proj MFMA ------
        #pragma unroll
        for (int mt = 0; mt < 4; ++mt) {
            uint4 hq;
            hq.x = pk2(silu(acc[0][mt][0]) * gacc[0][mt][0],
                       silu(acc[0][mt][1]) * gacc[0][mt][1]);
            hq.y = pk2(silu(acc[0][mt][2]) * gacc[0][mt][2],
                       silu(acc[0][mt][3]) * gacc[0][mt][3]);
            hq.z = pk2(silu(acc[1][mt][0]) * gacc[1][mt][0],
                       silu(acc[1][mt][1]) * gacc[1][mt][1]);
            hq.w = pk2(silu(acc[1][mt][2]) * gacc[1][mt][2],
                       silu(acc[1][mt][3]) * gacc[1][mt][3]);
            oacc[mt] = mfma16(obf, *(bf16x8*)&hq, oacc[mt]);
        }
    }
    __syncthreads();   // all afrag reads complete; smem becomes red

    // ---- write per-wave out-proj partials ---------------------------------
    #pragma unroll
    for (int mt = 0; mt < 4; ++mt)
        *(f32x4*)&redf[((wave * 4 + mt) * 64 + lane) * 4] = oacc[mt];
    __syncthreads();

    // ---- final 8-way reduce + write ---------------------------------------
    {
        int head = t >> 6, el = t & 63;          // 8 heads x 64 edges
        int mt = el >> 4, c = el & 15;
        int l  = (head >> 2) * 16 + c;           // quad = head>>2
        int r  = head & 3;
        float s = 0.f;
        #pragma unroll
        for (int w = 0; w < 8; ++w)
            s += redf[((w * 4 + mt) * 64 + l) * 4 + r];
        int eg = e0 + el;
        if (eg < E) out[head * E + eg] = s + b_out[head];
    }
}

extern "C" void kernel_launch(void* const* d_in, const int* in_sizes, int n_in,
                              void* d_out, int out_size, void* d_ws, size_t ws_size,
                              hipStream_t stream) {
    const int*   anum        = (const int*)d_in[0];
    const int*   edge_index  = (const int*)d_in[1];
    const int*   edge_to_src = (const int*)d_in[2];
    const float* dist        = (const float*)d_in[3];
    const float* emb_table   = (const float*)d_in[4];
    const float* gate_W      = (const float*)d_in[5];
    const float* W_in        = (const float*)d_in[6];
    const float* b_in        = (const float*)d_in[7];
    const float* W_out       = (const float*)d_in[8];
    const float* b_out       = (const float*)d_in[9];
    const int E   = in_sizes[3];
    const int TBL = in_sizes[4];               // NELEM^2 * EMBED elements

    u16* Wb = (u16*)d_ws;
    u16* Gb = Wb + WB_ELEMS;
    u16* Ob = Gb + GB_ELEMS;
    u16* Eb = Ob + OB_ELEMS;

    const size_t need_bf16 = (size_t)(WEIGHT_ELEMS + TBL) * sizeof(u16);
    const bool use_bf16_table = ws_size >= need_bf16;

    const int nconv = TBL / 8;                 // 8 floats per conv thread
    const int total = WEIGHT_ELEMS + (use_bf16_table ? nconv : 0);
    prep_all_kernel<<<(total + 255) / 256, 256, 0, stream>>>(
        W_in, gate_W, W_out, b_in, emb_table,
        Wb, Gb, Ob, (uint*)Eb, nconv, use_bf16_table ? 1 : 0);

    const int nblocks = (E + M - 1) / M;
    if (use_bf16_table) {
        pair_embed_kernel<true><<<nblocks, THREADS, 0, stream>>>(
            anum, edge_index, edge_to_src, dist, emb_table, Eb,
            b_out, Wb, Gb, Ob, (float*)d_out, E);
    } else {
        pair_embed_kernel<false><<<nblocks, THREADS, 0, stream>>>(
            anum, edge_index, edge_to_src, dist, emb_table, Eb,
            b_out, Wb, Gb, Ob, (float*)d_out, E);
    }
}

// Round 11
// 259.457 us; speedup vs baseline: 1.5250x; 1.5250x over previous
//
#include <hip/hip_runtime.h>
#include <hip/hip_bf16.h>

typedef unsigned short u16;
typedef unsigned int   uint;
typedef __attribute__((ext_vector_type(8))) short bf16x8;
typedef __attribute__((ext_vector_type(4))) float f32x4;

constexpr int NELEM = 100;
constexpr int EMBED = 256;
constexpr int HID   = 512;
constexpr int KX    = 306;     // EMBED + 50
constexpr int G     = 50;
constexpr int M     = 64;      // edges per block
constexpr int THREADS = 512;   // 8 waves

// frag-ready weight buffers in d_ws (bf16):
//  Wb : [32 nt][10 ks][64 lane][8]   (k==306 row carries b_in; >306 zero)
//  Gb : [32 nt][ 2 ks][64 lane][8]   (g>=50 zero)
//  Ob : [16 slice][64 lane][8]       permuted W_out for in-register out-proj
//  Eb : emb_table converted to bf16 (if ws fits)
constexpr int WB_ELEMS = 32 * 10 * 64 * 8;
constexpr int GB_ELEMS = 32 * 2 * 64 * 8;
constexpr int OB_ELEMS = 16 * 64 * 8;
constexpr int WEIGHT_ELEMS = WB_ELEMS + GB_ELEMS + OB_ELEMS;   // 204800

__device__ __forceinline__ u16 f2bf(float x) {
    uint u = __float_as_uint(x);
    u = (u + 0x7fffu + ((u >> 16) & 1u)) >> 16;
    return (u16)u;
}
__device__ __forceinline__ uint pk2(float a, float b) {
    __hip_bfloat162 h = __float22bfloat162_rn(make_float2(a, b));
    return *reinterpret_cast<uint*>(&h);
}
__device__ __forceinline__ float silu(float p) {
    return p * __builtin_amdgcn_rcpf(1.f + __expf(-p));
}
__device__ __forceinline__ f32x4 mfma16(bf16x8 a, bf16x8 b, f32x4 c) {
    return __builtin_amdgcn_mfma_f32_16x16x32_bf16(a, b, c, 0, 0, 0);
}
__device__ __forceinline__ void load_lds16(const u16* g, u16* l) {
    __builtin_amdgcn_global_load_lds(
        (const __attribute__((address_space(1))) uint*)g,
        (__attribute__((address_space(3))) uint*)l, 16, 0, 0);
}

// ---- prep: weights -> frag layouts, plus emb_table f32->bf16 (fused) -------
__global__ void prep_all_kernel(const float* __restrict__ W_in,   // [512][306]
                                const float* __restrict__ gate_W, // [512][50]
                                const float* __restrict__ W_out,  // [8][512]
                                const float* __restrict__ b_in,   // [512]
                                const float* __restrict__ table,  // emb f32
                                u16* __restrict__ Wb,
                                u16* __restrict__ Gb,
                                u16* __restrict__ Ob,
                                uint* __restrict__ Eb4,           // bf16 table
                                int nconv, int do_conv) {
    int idx = blockIdx.x * 256 + threadIdx.x;
    if (idx < WB_ELEMS) {
        int j = idx & 7, lane = (idx >> 3) & 63, kn = idx >> 9;
        int ks = kn % 10, nt = kn / 10;
        int h = nt * 16 + (lane & 15);
        int k = ks * 32 + (lane >> 4) * 8 + j;
        float v = (k < KX) ? W_in[h * KX + k] : ((k == KX) ? b_in[h] : 0.f);
        Wb[idx] = f2bf(v);
    } else if (idx < WB_ELEMS + GB_ELEMS) {
        int i2 = idx - WB_ELEMS;
        int j = i2 & 7, lane = (i2 >> 3) & 63, kn = i2 >> 9;
        int ks = kn & 1, nt = kn >> 1;
        int h = nt * 16 + (lane & 15);
        int g = ks * 32 + (lane >> 4) * 8 + j;
        Gb[i2] = f2bf((g < G) ? gate_W[h * G + g] : 0.f);
    } else if (idx < WEIGHT_ELEMS) {
        int i2 = idx - WB_ELEMS - GB_ELEMS;
        int j = i2 & 7, lane = (i2 >> 3) & 63, s = i2 >> 9;
        int m = lane & 15, q = lane >> 4;
        int hid = s * 32 + (j >> 2) * 16 + q * 4 + (j & 3);
        Ob[i2] = f2bf((m < 8) ? W_out[m * HID + hid] : 0.f);
    } else if (do_conv) {
        int i = idx - WEIGHT_ELEMS;          // one thread = 8 floats -> uint4
        if (i < nconv) {
            const float4* s4 = (const float4*)(table + i * 8);
            float4 v0 = s4[0], v1 = s4[1];
            uint4 w;
            w.x = pk2(v0.x, v0.y); w.y = pk2(v0.z, v0.w);
            w.z = pk2(v1.x, v1.y); w.w = pk2(v1.z, v1.w);
            ((uint4*)Eb4)[i] = w;
        }
    }
}

// ---- fused main kernel (r7-proven structure + setprio around compute) ------
// Math/accumulation order identical to r7/r0. The only delta vs r7 (204.6 us):
// s_setprio(1) around the MFMA-dense region so compute-phase waves win issue
// arbitration over staging-phase waves of co-resident blocks (3 blocks/CU).
template <bool BF16_TABLE>
__global__ __launch_bounds__(THREADS, 4)
void pair_embed_kernel(const int* __restrict__ anum,
                       const int* __restrict__ edge_index,
                       const int* __restrict__ edge_to_src,
                       const float* __restrict__ dist,
                       const float* __restrict__ emb_table,
                       const u16* __restrict__ Eb,
                       const float* __restrict__ b_out,
                       const u16* __restrict__ Wb,
                       const u16* __restrict__ Gb,
                       const u16* __restrict__ Ob,
                       float* __restrict__ out,
                       int E) {
    // afrag [10 ks][4 mt][64 lane][8] = 40 KB; red (32 KB) unions into it.
    __shared__ __align__(16) u16 smem[10 * 4 * 64 * 8];
    __shared__ int   rowbase[M];
    __shared__ float dste[M];
    u16*   afrag = smem;
    float* redf  = (float*)smem;     // [8 wave][4 mt][64 lane][4]

    const int t  = threadIdx.x;
    const int e0 = blockIdx.x * M;
    const int wave = t >> 6, lane = t & 63;
    const int col = lane & 15, quad = lane >> 4;

    if (t < M) {
        int eg = e0 + t;
        int pair = 0; float d = 0.f;
        if (eg < E) {
            int src = edge_to_src[eg];
            pair = anum[edge_index[src]] + NELEM * anum[edge_index[E + src]];
            d = dist[eg];
        }
        rowbase[t] = pair * EMBED;
        dste[t]    = d;
    }
    __syncthreads();

    // ---- stage A-tile -----------------------------------------------------
    {
        if (BF16_TABLE) {
            #pragma unroll
            for (int mt = 0; mt < 4; ++mt) {
                int rb = rowbase[mt * 16 + col];
                const u16* g = Eb + rb + wave * 32 + quad * 8;
                load_lds16(g, &afrag[((wave * 4 + mt) * 64 + lane) * 8]);
            }
        } else {
            #pragma unroll 1
            for (int mt = 0; mt < 4; ++mt) {
                int rb = rowbase[mt * 16 + col];
                const float4* src = (const float4*)(emb_table + rb + wave * 32 + quad * 8);
                float4 v0 = src[0], v1 = src[1];
                uint4 w;
                w.x = pk2(v0.x, v0.y); w.y = pk2(v0.z, v0.w);
                w.z = pk2(v1.x, v1.y); w.w = pk2(v1.z, v1.w);
                *(uint4*)&afrag[((wave * 4 + mt) * 64 + lane) * 8] = w;
            }
        }
        // rbf + bias chunk: one per wave: ks = 8+(wave&1), mt = wave>>1
        {
            const float sp    = 12.0f / 49.0f;
            const float coeff = -0.5f / (sp * sp);
            int ksr = 8 + (wave & 1), mtr = wave >> 1;
            float d  = dste[mtr * 16 + col];
            int   k0 = ksr * 32 + quad * 8;
            float f[8];
            #pragma unroll
            for (int j = 0; j < 8; ++j) {
                int k = k0 + j;
                int g = k - EMBED;
                float dd = d - sp * (float)g;
                f[j] = (g < G) ? __expf(coeff * dd * dd) : ((k == KX) ? 1.f : 0.f);
            }
            uint4 w;
            w.x = pk2(f[0], f[1]); w.y = pk2(f[2], f[3]);
            w.z = pk2(f[4], f[5]); w.w = pk2(f[6], f[7]);
            *(uint4*)&afrag[((ksr * 4 + mtr) * 64 + lane) * 8] = w;
        }
    }
    __syncthreads();

    const f32x4 z4 = {0.f, 0.f, 0.f, 0.f};
    f32x4 oacc[4] = {z4, z4, z4, z4};        // out-proj partials, D[head][edge]

    __builtin_amdgcn_s_setprio(1);           // favor compute-phase waves
    #pragma unroll
    for (int nh = 0; nh < 2; ++nh) {
        f32x4 acc[2][4], gacc[2][4];
        #pragma unroll
        for (int ntl = 0; ntl < 2; ++ntl)
            #pragma unroll
            for (int mt = 0; mt < 4; ++mt) { acc[ntl][mt] = z4; gacc[ntl][mt] = z4; }

        const u16* wb0 = &Wb[(((wave * 4 + nh * 2 + 0) * 10) * 64 + lane) * 8];
        const u16* wb1 = &Wb[(((wave * 4 + nh * 2 + 1) * 10) * 64 + lane) * 8];
        const u16* gb  = &Gb[((wave * 4 + nh * 2) * 2 * 64 + lane) * 8];

        // ---- emb part: ks 0..7 (main GEMM only) ----------------------------
        #pragma unroll 2
        for (int ks = 0; ks < 8; ++ks) {
            bf16x8 a[4];
            #pragma unroll
            for (int mt = 0; mt < 4; ++mt)
                a[mt] = *(const bf16x8*)&afrag[((ks * 4 + mt) * 64 + lane) * 8];
            bf16x8 w0 = *(const bf16x8*)&wb0[ks * 512];
            #pragma unroll
            for (int mt = 0; mt < 4; ++mt)
                acc[0][mt] = mfma16(w0, a[mt], acc[0][mt]);
            bf16x8 w1 = *(const bf16x8*)&wb1[ks * 512];
            #pragma unroll
            for (int mt = 0; mt < 4; ++mt)
                acc[1][mt] = mfma16(w1, a[mt], acc[1][mt]);
        }

        // ---- rbf part: ks 8..9, gate + main share the A-fragments ----------
        #pragma unroll
        for (int ks2 = 0; ks2 < 2; ++ks2) {
            const int ks = 8 + ks2;
            bf16x8 a[4];
            #pragma unroll
            for (int mt = 0; mt < 4; ++mt)
                a[mt] = *(const bf16x8*)&afrag[((ks * 4 + mt) * 64 + lane) * 8];
            bf16x8 g0f = *(const bf16x8*)&gb[ks2 * 512];
            bf16x8 w0f = *(const bf16x8*)&wb0[ks * 512];
            bf16x8 g1f = *(const bf16x8*)&gb[1024 + ks2 * 512];
            bf16x8 w1f = *(const bf16x8*)&wb1[ks * 512];
            #pragma unroll
            for (int mt = 0; mt < 4; ++mt) gacc[0][mt] = mfma16(g0f, a[mt], gacc[0][mt]);
            #pragma unroll
            for (int mt = 0; mt < 4; ++mt) acc[0][mt]  = mfma16(w0f, a[mt], acc[0][mt]);
            #pragma unroll
            for (int mt = 0; mt < 4; ++mt) gacc[1][mt] = mfma16(g1f, a[mt], gacc[1][mt]);
            #pragma unroll
            for (int mt = 0; mt < 4; ++mt) acc[1][mt]  = mfma16(w1f, a[mt], acc[1][mt]);
        }

        // ---- silu * gate (f32) -> h-frag (B-operand) -> out-proj MFMA ------
        bf16x8 obf = *(const bf16x8*)&Ob[(((wave << 1) | nh) * 64 + lane) * 8];
        #pragma unroll
        for (int mt = 0; mt < 4; ++mt) {
            uint4 hq;
            hq.x = pk2(silu(acc[0][mt][0]) * gacc[0][mt][0],
                       silu(acc[0][mt][1]) * gacc[0][mt][1]);
            hq.y = pk2(silu(acc[0][mt][2]) * gacc[0][mt][2],
                       silu(acc[0][mt][3]) * gacc[0][mt][3]);
            hq.z = pk2(silu(acc[1][mt][0]) * gacc[1][mt][0],
                       silu(acc[1][mt][1]) * gacc[1][mt][1]);
            hq.w = pk2(silu(acc[1][mt][2]) * gacc[1][mt][2],
                       silu(acc[1][mt][3]) * gacc[1][mt][3]);
            oacc[mt] = mfma16(obf, *(bf16x8*)&hq, oacc[mt]);
        }
    }
    __builtin_amdgcn_s_setprio(0);
    __syncthreads();   // all afrag reads complete; smem becomes red

    // ---- write per-wave out-proj partials ---------------------------------
    #pragma unroll
    for (int mt = 0; mt < 4; ++mt)
        *(f32x4*)&redf[((wave * 4 + mt) * 64 + lane) * 4] = oacc[mt];
    __syncthreads();

    // ---- final 8-way reduce + write ---------------------------------------
    {
        int head = t >> 6, el = t & 63;          // 8 heads x 64 edges
        int mt = el >> 4, c = el & 15;
        int l  = (head >> 2) * 16 + c;           // quad = head>>2
        int r  = head & 3;
        float s = 0.f;
        #pragma unroll
        for (int w = 0; w < 8; ++w)
            s += redf[((w * 4 + mt) * 64 + l) * 4 + r];
        int eg = e0 + el;
        if (eg < E) out[head * E + eg] = s + b_out[head];
    }
}

extern "C" void kernel_launch(void* const* d_in, const int* in_sizes, int n_in,
                              void* d_out, int out_size, void* d_ws, size_t ws_size,
                              hipStream_t stream) {
    const int*   anum        = (const int*)d_in[0];
    const int*   edge_index  = (const int*)d_in[1];
    const int*   edge_to_src = (const int*)d_in[2];
    const float* dist        = (const float*)d_in[3];
    const float* emb_table   = (const float*)d_in[4];
    const float* gate_W      = (const float*)d_in[5];
    const float* W_in        = (const float*)d_in[6];
    const float* b_in        = (const float*)d_in[7];
    const float* W_out       = (const float*)d_in[8];
    const float* b_out       = (const float*)d_in[9];
    const int E   = in_sizes[3];
    const int TBL = in_sizes[4];               // NELEM^2 * EMBED elements

    u16* Wb = (u16*)d_ws;
    u16* Gb = Wb + WB_ELEMS;
    u16* Ob = Gb + GB_ELEMS;
    u16* Eb = Ob + OB_ELEMS;

    const size_t need_bf16 = (size_t)(WEIGHT_ELEMS + TBL) * sizeof(u16);
    const bool use_bf16_table = ws_size >= need_bf16;

    const int nconv = TBL / 8;                 // 8 floats per conv thread
    const int total = WEIGHT_ELEMS + (use_bf16_table ? nconv : 0);
    prep_all_kernel<<<(total + 255) / 256, 256, 0, stream>>>(
        W_in, gate_W, W_out, b_in, emb_table,
        Wb, Gb, Ob, (uint*)Eb, nconv, use_bf16_table ? 1 : 0);

    const int nblocks = (E + M - 1) / M;
    if (use_bf16_table) {
        pair_embed_kernel<true><<<nblocks, THREADS, 0, stream>>>(
            anum, edge_index, edge_to_src, dist, emb_table, Eb,
            b_out, Wb, Gb, Ob, (float*)d_out, E);
    } else {
        pair_embed_kernel<false><<<nblocks, THREADS, 0, stream>>>(
            anum, edge_index, edge_to_src, dist, emb_table, Eb,
            b_out, Wb, Gb, Ob, (float*)d_out, E);
    }
}